// Round 8
// baseline (272.527 us; speedup 1.0000x reference)
//
#include <hip/hip_runtime.h>

#define NROW 6
#define NCOL 6
#define BATCH 1024
#define NSITE 36

// LDS bank-conflict swizzle: XOR dword-addr bits [4:2] with bits [7:5].
// Preserves bits [1:0]; constant within any aligned 4-dword window; SWZ(0)==0.
__device__ __forceinline__ int SWZ(int a) { return a ^ (((a >> 5) & 7) << 2); }

// Wave-uniform scalar-memory pointers: address_space(4) = AMDGPU constant.
// Scalar/double loads at uniform offsets merge into s_load_dwordx2/x4/x16
// (SMEM pipe) — R12 (prior session) proved this path; R7 proved moving M
// off SMEM regresses. M stays here.
typedef const float  __attribute__((address_space(4))) * fcp;
typedef const double __attribute__((address_space(4))) * dcp;

// R8: packed FP32 FMA, forced. R5 proved the compiler scalarizes v2f math
// (bit-identical counters to scalar R0), yet the measured VALU busy time
// (~75us = the 1024-FMA-instr/wave/phase issue stream at 2cyc) is the
// single biggest attributable term. v_pk_fma_f32 (VOP3P, gfx90a+) does 2
// MACs/instr. M broadcast costs nothing: load the aligned double holding
// {M[2k],M[2k+1]} into an SGPR pair and use op_sel to feed word0 (pk0) or
// word1 (pk1) of src0 to BOTH result halves. Same fused rounding, same
// accumulation order as R0 -> bitwise-identical output.
typedef float v2f __attribute__((ext_vector_type(2)));
typedef float v4f __attribute__((ext_vector_type(4)));

__device__ __forceinline__ void pk0(v2f& a, double m, v2f s) {
    asm("v_pk_fma_f32 %0, %1, %2, %0 op_sel:[0,0,0] op_sel_hi:[0,1,1]"
        : "+v"(a) : "s"(m), "v"(s));
}
__device__ __forceinline__ void pk1(v2f& a, double m, v2f s) {
    asm("v_pk_fma_f32 %0, %1, %2, %0 op_sel:[1,0,0] op_sel_hi:[1,1,1]"
        : "+v"(a) : "s"(m), "v"(s));
}
__device__ __forceinline__ v2f lo2(v4f q) { return __builtin_shufflevector(q, q, 0, 1); }
__device__ __forceinline__ v2f hi2(v4f q) { return __builtin_shufflevector(q, q, 2, 3); }
__device__ __forceinline__ v4f cat4(v2f l, v2f h) { return __builtin_shufflevector(l, h, 0, 1, 2, 3); }

// Pre-transpose T[site][spin][u=x][r=gp][d=z][l=g] into
// Tm[(site*2+spin)*256 + (gp*4+z)*16 + (g*4+x)]  (73,728 B in d_ws).
__global__ void peps_reorder_kernel(const float* __restrict__ T,
                                    float* __restrict__ Tm)
{
    int idx = blockIdx.x * 256 + threadIdx.x;   // [0, 18432)
    if (idx >= NSITE * 2 * 256) return;
    int i  = idx & 15;          // i = g*4 + x
    int o  = (idx >> 4) & 15;   // o = gp*4 + z
    int sp = (idx >> 8) & 1;
    int st = idx >> 9;
    int g = i >> 2, x = i & 3, gp = o >> 2, z = o & 3;
    Tm[idx] = T[st * 512 + sp * 256 + x * 64 + gp * 16 + z * 4 + g];
}

// One step body, 4 SPECTATORS PER THREAD (u = 4t..4t+3) packed as two v2f
// lanes {u0,u1},{u2,u3}; fully specialized, one divergent branch. Identical
// arithmetic/order to the verified R0 body — only the MAC emission changed
// (forced v_pk_fma_f32, SGPR-pair M with op_sel broadcast). M row base as
// double index: mbd = (gp*4+z)*8; pair g*2 holds x{0,1}, g*2+1 holds x{2,3}.
template<int GIN, int GOUT, int XS, int ZS, bool C0>
__device__ __forceinline__ void do_step4(float* __restrict__ W, const fcp Msf,
                                         const int* __restrict__ A, int p4c,
                                         bool act)
{
    if (!act) return;
    const dcp Md = (dcp)Msf;
    v2f in2[2][16];              // [spect-pair][g*4+x]
    // ---- read phase (verbatim R5) ----
    if (C0) {                    // GIN==1; x (or z) is the low address digit
        if (XS == 4) {           // per-spectator x-quads -> transpose to pairs
            v4f q0 = *(const v4f*)&W[A[0]];
            v4f q1 = *(const v4f*)&W[A[1]];
            v4f q2 = *(const v4f*)&W[A[2]];
            v4f q3 = *(const v4f*)&W[A[3]];
            #pragma unroll
            for (int x = 0; x < 4; ++x) {
                v2f a, b;
                a[0] = q0[x]; a[1] = q1[x]; in2[0][x] = a;
                b[0] = q2[x]; b[1] = q3[x]; in2[1][x] = b;
            }
        } else {
            v2f a, b;
            a[0] = W[A[0]]; a[1] = W[A[1]]; in2[0][0] = a;
            b[0] = W[A[2]]; b[1] = W[A[3]]; in2[1][0] = b;
        }
    } else if (ZS == 4) {        // spectator quad contiguous at A[x]: free pack
        #pragma unroll
        for (int g = 0; g < GIN; ++g)
            #pragma unroll
            for (int x = 0; x < XS; ++x) {
                v4f q = *(const v4f*)&W[A[x] + g * 4096];
                in2[0][g*4+x] = lo2(q);
                in2[1][g*4+x] = hi2(q);
            }
    } else {                     // row5 c>=1: scattered scalars (tiny work)
        #pragma unroll
        for (int g = 0; g < GIN; ++g)
            #pragma unroll
            for (int x = 0; x < XS; ++x) {
                v2f a, b;
                a[0] = W[SWZ(x * p4c + A[0]) + g * 4096];
                a[1] = W[SWZ(x * p4c + A[1]) + g * 4096];
                b[0] = W[SWZ(x * p4c + A[2]) + g * 4096];
                b[1] = W[SWZ(x * p4c + A[3]) + g * 4096];
                in2[0][g*4+x] = a; in2[1][g*4+x] = b;
            }
    }
    // ---- compute + write (in-place; same address set) ----
    #pragma unroll
    for (int gp = 0; gp < GOUT; ++gp) {
        v2f a2[ZS][2];
        #pragma unroll
        for (int z = 0; z < ZS; ++z) {
            const int mbd = (gp * 4 + z) * 8;    // M row base, double units
            a2[z][0] = (v2f)0.f; a2[z][1] = (v2f)0.f;
            #pragma unroll
            for (int g = 0; g < GIN; ++g) {
                if (XS == 4) {
                    const double m01 = Md[mbd + g * 2];      // {x0,x1}
                    const double m23 = Md[mbd + g * 2 + 1];  // {x2,x3}
                    pk0(a2[z][0], m01, in2[0][g*4+0]);
                    pk0(a2[z][1], m01, in2[1][g*4+0]);
                    pk1(a2[z][0], m01, in2[0][g*4+1]);
                    pk1(a2[z][1], m01, in2[1][g*4+1]);
                    pk0(a2[z][0], m23, in2[0][g*4+2]);
                    pk0(a2[z][1], m23, in2[1][g*4+2]);
                    pk1(a2[z][0], m23, in2[0][g*4+3]);
                    pk1(a2[z][1], m23, in2[1][g*4+3]);
                } else {         // XS==1: word0 of the aligned pair is M
                    const double m0 = Md[mbd + g * 2];
                    pk0(a2[z][0], m0, in2[0][g*4]);
                    pk0(a2[z][1], m0, in2[1][g*4]);
                }
            }
        }
        if (C0 && ZS == 4) {     // transpose back: one quad per spectator
            #pragma unroll
            for (int i = 0; i < 4; ++i) {
                v4f r;
                r[0] = a2[0][i >> 1][i & 1];
                r[1] = a2[1][i >> 1][i & 1];
                r[2] = a2[2][i >> 1][i & 1];
                r[3] = a2[3][i >> 1][i & 1];
                *(v4f*)&W[A[i] + gp * 4096] = r;
            }
        } else if (ZS == 4) {    // pairs re-concatenate for free
            #pragma unroll
            for (int z = 0; z < 4; ++z)
                *(v4f*)&W[A[z] + gp * 4096] = cat4(a2[z][0], a2[z][1]);
        } else if (C0) {         // row5 c0: z collapses, base address
            #pragma unroll
            for (int i = 0; i < 4; ++i)
                W[A[i] + gp * 4096] = a2[0][i >> 1][i & 1];
        } else {                 // row5 c>=1
            #pragma unroll
            for (int i = 0; i < 4; ++i)
                W[SWZ(A[i]) + gp * 4096] = a2[0][i >> 1][i & 1];
        }
    }
}

// Fixed-slot in-place contraction (verified R8..R16 + R0 algebra): state
// index = g*4096 + sum_j slot_j*4^j; step (row,c) reads up-bond x from slot c
// and writes down-bond z back into the same slot. ONE barrier/step. State in
// LDS (64 KB, swizzled). scount=1 steps: (0,0)'s stray spectator writes land
// in W[4..15](+gp*4096), fully overwritten by step (0,1) before (0,2) reads
// them; (5,5) is last (only W[0] read). 256 threads x 4 spectators; 2
// blocks/CU (LDS-bound), 8 waves/CU. Loops fully unrolled (R6 proved the
// wide scheduling window is worth the code size).
__global__ __launch_bounds__(256, 2)
void peps_amp_kernel(const int* __restrict__ X, const float* __restrict__ Tm,
                     float* __restrict__ out)
{
    __shared__ float W[16384];   // 65536 B exactly (4^7 fixed-slot state)

    const int b = blockIdx.x;
    const int t = threadIdx.x;
    const int u0 = 4 * t;        // this thread's spectators: u0..u0+3
    const int* xrow = X + b * NSITE;

    // PHYS=2: pack the 36 spins into one scalar 64-bit mask (SGPR-resident
    // so every Tm address below is provably wave-uniform).
    unsigned long long sm = 0ull;
    const int4* xp = (const int4*)xrow;
    #pragma unroll
    for (int k = 0; k < 9; ++k) {
        int4 v = xp[k];
        sm |= ((unsigned long long)(v.x & 1)) << (4 * k + 0);
        sm |= ((unsigned long long)(v.y & 1)) << (4 * k + 1);
        sm |= ((unsigned long long)(v.z & 1)) << (4 * k + 2);
        sm |= ((unsigned long long)(v.w & 1)) << (4 * k + 3);
    }
    {
        unsigned lo = __builtin_amdgcn_readfirstlane((int)(sm & 0xffffffffull));
        unsigned hi = __builtin_amdgcn_readfirstlane((int)(sm >> 32));
        sm = ((unsigned long long)hi << 32) | lo;
    }

    if (t == 0) W[0] = 1.0f;     // seed (SWZ(0)==0); covered by step-0 barrier

    int step = 0;
    for (int row = 0; row < NROW; ++row) {
        const int xs = (row == 0) ? 1 : 4;          // up-bond size
        const int zs = (row == NROW - 1) ? 1 : 4;   // down-bond size
        for (int c = 0; c < NCOL; ++c, ++step) {
            const int lowb  = (zs == 4) ? 2 * c : 0;
            const int highb = (xs == 4) ? 2 * (5 - c) : 0;
            const int scount = 1 << (lowb + highb);
            const int p4c = 1 << (2 * c);
            const int lowmask = (1 << lowb) - 1;
            const bool act = (u0 < scount);

            // uniform scalar: spin bit + M base for this step (SMEM pointer)
            const int spin = (int)((sm >> step) & 1ull);
            const fcp Msf = (fcp)(unsigned long long)
                (const void*)(Tm + (size_t)(step * 2 + spin) * 256);

            __syncthreads();     // the ONLY barrier per step

            // per-thread LDS addresses (quad-aligned where vectorized)
            int A[4];
            if (c == 0) {
                #pragma unroll
                for (int i = 0; i < 4; ++i) A[i] = SWZ(16 * t + 4 * i);
            } else if (zs == 4) {
                const int mr0 = ((u0 >> lowb) << (2 * c + 2)) | (u0 & lowmask);
                #pragma unroll
                for (int d = 0; d < 4; ++d) A[d] = SWZ(d * p4c + mr0);
            } else {             // row5 c>=1: per-spectator bases, unswizzled
                #pragma unroll
                for (int i = 0; i < 4; ++i) A[i] = (u0 + i) << (2 * c + 2);
            }

            // uniform 3x3 dispatch to branch-free specialized bodies
            if (row == 0) {
                if (c == 0)            do_step4<1,4,1,4,true >(W, Msf, A, p4c, act);
                else if (c < NCOL - 1) do_step4<4,4,1,4,false>(W, Msf, A, p4c, act);
                else                   do_step4<4,1,1,4,false>(W, Msf, A, p4c, act);
            } else if (row < NROW - 1) {
                if (c == 0)            do_step4<1,4,4,4,true >(W, Msf, A, p4c, act);
                else if (c < NCOL - 1) do_step4<4,4,4,4,false>(W, Msf, A, p4c, act);
                else                   do_step4<4,1,4,4,false>(W, Msf, A, p4c, act);
            } else {
                if (c == 0)            do_step4<1,4,4,1,true >(W, Msf, A, p4c, act);
                else if (c < NCOL - 1) do_step4<4,4,4,1,false>(W, Msf, A, p4c, act);
                else                   do_step4<4,1,4,1,false>(W, Msf, A, p4c, act);
            }
        }
    }
    __syncthreads();
    // after (5,5): only g'=0, z=0, u=0 live -> the amplitude sits at W[0]
    if (t == 0) out[b] = W[0];
}

extern "C" void kernel_launch(void* const* d_in, const int* in_sizes, int n_in,
                              void* d_out, int out_size, void* d_ws, size_t ws_size,
                              hipStream_t stream) {
    const int*   X  = (const int*)d_in[0];     // x: [1024, 36] int32
    const float* Tg = (const float*)d_in[1];   // T: [6,6,2,4,4,4,4] fp32
    float* out = (float*)d_out;                // reference output: float32
    float* Tm  = (float*)d_ws;                 // 73,728 B scratch
    (void)in_sizes; (void)n_in; (void)ws_size; (void)out_size;
    peps_reorder_kernel<<<dim3(72), dim3(256), 0, stream>>>(Tg, Tm);
    peps_amp_kernel<<<dim3(BATCH), dim3(256), 0, stream>>>(X, Tm, out);
}

// Round 9
// 186.569 us; speedup vs baseline: 1.4607x; 1.4607x over previous
//
#include <hip/hip_runtime.h>

#define NROW 6
#define NCOL 6
#define BATCH 1024
#define NSITE 36

// LDS bank-conflict swizzle: XOR dword-addr bits [4:2] with bits [7:5].
// Preserves bits [1:0]; constant within any aligned 4-dword window; SWZ(0)==0.
__device__ __forceinline__ int SWZ(int a) { return a ^ (((a >> 5) & 7) << 2); }

// Wave-uniform scalar-memory pointer: address_space(4) = AMDGPU constant.
// Scalar float loads at uniform offsets merge into s_load_dwordx4/x16 (SMEM
// pipe, one fetch per wave). R4 (LDS-M), R7 (VMEM-M) both regressed: M stays
// on SMEM. R8 proved v_pk_fma_f32 does NOT double FP32 rate on gfx950 —
// the ~75us VALU busy time is the FP32 issue floor for this decomposition.
typedef const float __attribute__((address_space(4))) * fcp;

__device__ __forceinline__ fcp msel(const float* Tm, int step,
                                    unsigned long long sm) {
    int spin = (int)((sm >> step) & 1ull);
    return (fcp)(unsigned long long)(const void*)
        (Tm + (size_t)(step * 2 + spin) * 256);
}

// Pre-transpose T[site][spin][u=x][r=gp][d=z][l=g] into
// Tm[(site*2+spin)*256 + (gp*4+z)*16 + (g*4+x)]  (73,728 B in d_ws).
__global__ void peps_reorder_kernel(const float* __restrict__ T,
                                    float* __restrict__ Tm)
{
    int idx = blockIdx.x * 256 + threadIdx.x;   // [0, 18432)
    if (idx >= NSITE * 2 * 256) return;
    int i  = idx & 15;          // i = g*4 + x
    int o  = (idx >> 4) & 15;   // o = gp*4 + z
    int sp = (idx >> 8) & 1;
    int st = idx >> 9;
    int g = i >> 2, x = i & 3, gp = o >> 2, z = o & 3;
    Tm[idx] = T[st * 512 + sp * 256 + x * 64 + gp * 16 + z * 4 + g];
}

// One MIDDLE-ROW step body, 4 SPECTATORS PER THREAD (u = 4t..4t+3) —
// verbatim R0 (harness-verified). Rows 1..4 only: ZS==4 always, act always
// true (scount==1024), so the masked/row5 paths are never taken but kept
// for template completeness.
template<int GIN, int GOUT, int XS, int ZS, bool C0>
__device__ __forceinline__ void do_step4(float* __restrict__ W, const fcp Msf,
                                         const int* __restrict__ A, int p4c)
{
    float in_s[4][16];           // [spectator][g*4+x]
    // ---- read phase ----
    if (C0) {                    // GIN==1; x is the low address digit
        #pragma unroll
        for (int i = 0; i < 4; ++i) {
            float4 q = *(const float4*)&W[A[i]];
            in_s[i][0] = q.x; in_s[i][1] = q.y;
            in_s[i][2] = q.z; in_s[i][3] = q.w;
        }
    } else {                     // spectator quad contiguous at A[x]
        #pragma unroll
        for (int g = 0; g < GIN; ++g)
            #pragma unroll
            for (int x = 0; x < XS; ++x) {
                float4 q = *(const float4*)&W[A[x] + g * 4096];
                in_s[0][g*4+x] = q.x; in_s[1][g*4+x] = q.y;
                in_s[2][g*4+x] = q.z; in_s[3][g*4+x] = q.w;
            }
    }
    // ---- compute + write (in-place; same address set) ----
    #pragma unroll
    for (int gp = 0; gp < GOUT; ++gp) {
        float a[4][4];
        #pragma unroll
        for (int z = 0; z < 4; ++z) {
            const int mb = (gp * 4 + z) * 16;
            #pragma unroll
            for (int i = 0; i < 4; ++i) a[z][i] = 0.f;
            #pragma unroll
            for (int g = 0; g < GIN; ++g)
                #pragma unroll
                for (int x = 0; x < XS; ++x) {
                    const float m = Msf[mb + g * 4 + x];
                    #pragma unroll
                    for (int i = 0; i < 4; ++i)
                        a[z][i] += m * in_s[i][g*4+x];
                }
        }
        if (C0) {                // write per-spectator x-quads back
            #pragma unroll
            for (int i = 0; i < 4; ++i)
                *(float4*)&W[A[i] + gp * 4096] =
                    make_float4(a[0][i], a[1][i], a[2][i], a[3][i]);
        } else {
            #pragma unroll
            for (int z = 0; z < 4; ++z)
                *(float4*)&W[A[z] + gp * 4096] =
                    make_float4(a[z][0], a[z][1], a[z][2], a[z][3]);
        }
    }
}

// R9 = graft of the two harness-verified halves:
//   rows 1..4 : R0's fixed-slot in-place steps (6 phases/row, 1 barrier each)
//   row 0     : R2's fused chain — 3 cheap phases replace 6 FULL-width
//               phases that computed mostly junk under the stray-write
//               invariant ((0,0)..(0,5) all ran at scount=1024)
//   row 5     : R2's fused chain — 3 tiny phases replace 1 full + 5 masked
// Same layout (state idx = g*4096 + SWZ(sum slot_j*4^j)), same SWZ, same M
// path (SMEM), same 256x4 spectator map, 2 blocks/CU. Phases: 36 -> 30,
// junk FMA work (~7%) removed, seed + final barrier removed.
__global__ __launch_bounds__(256, 2)
void peps_amp_kernel(const int* __restrict__ X, const float* __restrict__ Tm,
                     float* __restrict__ out)
{
    __shared__ float W[16384];   // 65536 B exactly (4^7 fixed-slot state)

    const int b = blockIdx.x;
    const int t = threadIdx.x;
    const int u0 = 4 * t;        // this thread's spectators: u0..u0+3
    const int* xrow = X + b * NSITE;

    // PHYS=2: pack the 36 spins into one scalar 64-bit mask (SGPR-resident
    // so every Tm address below is provably wave-uniform).
    unsigned long long sm = 0ull;
    const int4* xp = (const int4*)xrow;
    #pragma unroll
    for (int k = 0; k < 9; ++k) {
        int4 v = xp[k];
        sm |= ((unsigned long long)(v.x & 1)) << (4 * k + 0);
        sm |= ((unsigned long long)(v.y & 1)) << (4 * k + 1);
        sm |= ((unsigned long long)(v.z & 1)) << (4 * k + 2);
        sm |= ((unsigned long long)(v.w & 1)) << (4 * k + 3);
    }
    {
        unsigned lo = __builtin_amdgcn_readfirstlane((int)(sm & 0xffffffffull));
        unsigned hi = __builtin_amdgcn_readfirstlane((int)(sm >> 32));
        sm = ((unsigned long long)hi << 32) | lo;
    }

    // ---- row 0 (R2-verified): (0,0)+(0,1) by thread 0 ----
    if (t == 0) {
        fcp M0 = msel(Tm, 0, sm), M1 = msel(Tm, 1, sm);
        float V[4][4];           // [gp][z0]  (seed state == 1.0)
        #pragma unroll
        for (int gp = 0; gp < 4; ++gp)
            #pragma unroll
            for (int z0 = 0; z0 < 4; ++z0)
                V[gp][z0] = M0[(gp * 4 + z0) * 16];
        #pragma unroll
        for (int gp1 = 0; gp1 < 4; ++gp1)
            #pragma unroll
            for (int z1 = 0; z1 < 4; ++z1) {
                float o[4];
                #pragma unroll
                for (int z0 = 0; z0 < 4; ++z0) {
                    float acc = 0.f;
                    #pragma unroll
                    for (int gp = 0; gp < 4; ++gp)
                        acc += M1[(gp1 * 4 + z1) * 16 + gp * 4] * V[gp][z0];
                    o[z0] = acc;
                }
                *(float4*)&W[gp1 * 4096 + SWZ(4 * z1)] =
                    make_float4(o[0], o[1], o[2], o[3]);
            }
    }
    __syncthreads();
    // ---- row 0: (0,2)+(0,3) by 16 threads (t = z0 + 4*z1) ----
    if (t < 16) {
        fcp M2 = msel(Tm, 2, sm), M3 = msel(Tm, 3, sm);
        float U[4];
        #pragma unroll
        for (int g = 0; g < 4; ++g) U[g] = W[g * 4096 + SWZ(t)];
        float V[4][4];           // [gp][z2]
        #pragma unroll
        for (int gp = 0; gp < 4; ++gp)
            #pragma unroll
            for (int z2 = 0; z2 < 4; ++z2) {
                float acc = 0.f;
                #pragma unroll
                for (int g = 0; g < 4; ++g)
                    acc += M2[(gp * 4 + z2) * 16 + g * 4] * U[g];
                V[gp][z2] = acc;
            }
        #pragma unroll
        for (int gp3 = 0; gp3 < 4; ++gp3)
            #pragma unroll
            for (int z3 = 0; z3 < 4; ++z3)
                #pragma unroll
                for (int z2 = 0; z2 < 4; ++z2) {
                    float acc = 0.f;
                    #pragma unroll
                    for (int gp = 0; gp < 4; ++gp)
                        acc += M3[(gp3 * 4 + z3) * 16 + gp * 4] * V[gp][z2];
                    W[gp3 * 4096 + SWZ(t + 16 * z2 + 64 * z3)] = acc;
                }
    }
    __syncthreads();
    // ---- row 0: (0,4)+(0,5) by all 256 threads (g collapses -> plane 0) --
    {
        fcp M4 = msel(Tm, 4, sm), M5 = msel(Tm, 5, sm);
        float U[4];
        #pragma unroll
        for (int g = 0; g < 4; ++g) U[g] = W[g * 4096 + SWZ(t)];
        float V[4][4];           // [gp][z4]
        #pragma unroll
        for (int gp = 0; gp < 4; ++gp)
            #pragma unroll
            for (int z4 = 0; z4 < 4; ++z4) {
                float acc = 0.f;
                #pragma unroll
                for (int g = 0; g < 4; ++g)
                    acc += M4[(gp * 4 + z4) * 16 + g * 4] * U[g];
                V[gp][z4] = acc;
            }
        #pragma unroll
        for (int z5 = 0; z5 < 4; ++z5)
            #pragma unroll
            for (int z4 = 0; z4 < 4; ++z4) {
                float acc = 0.f;
                #pragma unroll
                for (int gp = 0; gp < 4; ++gp)
                    acc += M5[z5 * 16 + gp * 4] * V[gp][z4];
                W[SWZ(t + 256 * z4 + 1024 * z5)] = acc;    // plane 0
            }
    }

    // ---- rows 1..4 (R0-verified): 6 in-place steps each, 1 barrier/step --
    int step = 6;
    for (int row = 1; row <= 4; ++row) {
        for (int c = 0; c < NCOL; ++c, ++step) {
            const int lowb = 2 * c;
            const int p4c = 1 << (2 * c);
            const int lowmask = (1 << lowb) - 1;
            const fcp Msf = msel(Tm, step, sm);

            __syncthreads();     // the ONLY barrier per step

            int A[4];
            if (c == 0) {
                #pragma unroll
                for (int i = 0; i < 4; ++i) A[i] = SWZ(16 * t + 4 * i);
            } else {
                const int mr0 = ((u0 >> lowb) << (2 * c + 2)) | (u0 & lowmask);
                #pragma unroll
                for (int d = 0; d < 4; ++d) A[d] = SWZ(d * p4c + mr0);
            }

            if (c == 0)            do_step4<1,4,4,4,true >(W, Msf, A, p4c);
            else if (c < NCOL - 1) do_step4<4,4,4,4,false>(W, Msf, A, p4c);
            else                   do_step4<4,1,4,4,false>(W, Msf, A, p4c);
        }
    }

    // ---- row 5 (R2-verified): (5,0)+(5,1) by all 256 threads ----
    __syncthreads();
    {
        fcp M0 = msel(Tm, 30, sm), M1 = msel(Tm, 31, sm);
        const int base = t << 4;
        float V[4][4];           // [gp][x1]
        #pragma unroll
        for (int x1 = 0; x1 < 4; ++x1) {
            float4 q = *(const float4*)&W[SWZ(base + 4 * x1)];
            float U[4] = {q.x, q.y, q.z, q.w};
            #pragma unroll
            for (int gp = 0; gp < 4; ++gp) {
                float acc = 0.f;
                #pragma unroll
                for (int x0 = 0; x0 < 4; ++x0)
                    acc += M0[gp * 64 + x0] * U[x0];
                V[gp][x1] = acc;
            }
        }
        #pragma unroll
        for (int gp1 = 0; gp1 < 4; ++gp1) {
            float acc = 0.f;
            #pragma unroll
            for (int gp = 0; gp < 4; ++gp)
                #pragma unroll
                for (int x1 = 0; x1 < 4; ++x1)
                    acc += M1[gp1 * 64 + gp * 4 + x1] * V[gp][x1];
            W[gp1 * 4096 + SWZ(base)] = acc;
        }
    }
    __syncthreads();
    // ---- row 5: (5,2)+(5,3) by 16 threads (t = x4 + 4*x5) ----
    if (t < 16) {
        fcp M2 = msel(Tm, 32, sm), M3 = msel(Tm, 33, sm);
        float V[4][4];           // [gp][x3]
        #pragma unroll
        for (int x3 = 0; x3 < 4; ++x3) {
            #pragma unroll
            for (int gp = 0; gp < 4; ++gp) V[gp][x3] = 0.f;
            #pragma unroll
            for (int x2 = 0; x2 < 4; ++x2) {
                float U[4];
                #pragma unroll
                for (int g = 0; g < 4; ++g)
                    U[g] = W[g * 4096 + SWZ((x2 + 4 * x3 + 16 * t) << 4)];
                #pragma unroll
                for (int gp = 0; gp < 4; ++gp)
                    #pragma unroll
                    for (int g = 0; g < 4; ++g)
                        V[gp][x3] += M2[gp * 64 + g * 4 + x2] * U[g];
            }
        }
        #pragma unroll
        for (int gp3 = 0; gp3 < 4; ++gp3) {
            float acc = 0.f;
            #pragma unroll
            for (int gp = 0; gp < 4; ++gp)
                #pragma unroll
                for (int x3 = 0; x3 < 4; ++x3)
                    acc += M3[gp3 * 64 + gp * 4 + x3] * V[gp][x3];
            W[gp3 * 4096 + SWZ(t << 8)] = acc;
        }
    }
    __syncthreads();
    // ---- row 5: (5,4)+(5,5) by thread 0 -> amplitude straight to out ----
    if (t == 0) {
        fcp M4 = msel(Tm, 34, sm), M5 = msel(Tm, 35, sm);
        float V[4][4];           // [gp][x5]
        #pragma unroll
        for (int x5 = 0; x5 < 4; ++x5) {
            #pragma unroll
            for (int gp = 0; gp < 4; ++gp) V[gp][x5] = 0.f;
            #pragma unroll
            for (int x4 = 0; x4 < 4; ++x4) {
                float U[4];
                #pragma unroll
                for (int g = 0; g < 4; ++g)
                    U[g] = W[g * 4096 + SWZ((x4 + 4 * x5) << 8)];
                #pragma unroll
                for (int gp = 0; gp < 4; ++gp)
                    #pragma unroll
                    for (int g = 0; g < 4; ++g)
                        V[gp][x5] += M4[gp * 64 + g * 4 + x4] * U[g];
            }
        }
        float r = 0.f;
        #pragma unroll
        for (int gp = 0; gp < 4; ++gp)
            #pragma unroll
            for (int x5 = 0; x5 < 4; ++x5)
                r += M5[gp * 4 + x5] * V[gp][x5];
        out[b] = r;
    }
}

extern "C" void kernel_launch(void* const* d_in, const int* in_sizes, int n_in,
                              void* d_out, int out_size, void* d_ws, size_t ws_size,
                              hipStream_t stream) {
    const int*   X  = (const int*)d_in[0];     // x: [1024, 36] int32
    const float* Tg = (const float*)d_in[1];   // T: [6,6,2,4,4,4,4] fp32
    float* out = (float*)d_out;                // reference output: float32
    float* Tm  = (float*)d_ws;                 // 73,728 B scratch
    (void)in_sizes; (void)n_in; (void)ws_size; (void)out_size;
    peps_reorder_kernel<<<dim3(72), dim3(256), 0, stream>>>(Tg, Tm);
    peps_amp_kernel<<<dim3(BATCH), dim3(256), 0, stream>>>(X, Tm, out);
}